// Round 11
// baseline (982.399 us; speedup 1.0000x reference)
//
#include <hip/hip_runtime.h>
#include <math.h>

typedef __attribute__((ext_vector_type(8))) short short8;
typedef __attribute__((ext_vector_type(4))) float v4f;
typedef __attribute__((ext_vector_type(4))) unsigned short us4;

#define INV_SCALE 0.07216878364870322f  // 1/sqrt(64*3)
#define NBLK 768u

__device__ __forceinline__ unsigned short f2bf(float f) {
  unsigned u = __builtin_bit_cast(unsigned, f);
  u = (u + 0x7FFFu + ((u >> 16) & 1u)) >> 16;  // RNE
  return (unsigned short)u;
}
__device__ __forceinline__ float bf2f(unsigned short h) {
  unsigned u = ((unsigned)h) << 16;
  return __builtin_bit_cast(float, u);
}

enum { OM_PLAIN = 0, OM_Q = 1, OM_K = 2, OM_VT = 3, OM_PK = 4, OM_PQ = 5 };

// Device-scope grid barrier (graph-capture-safe; no cooperative API).
// All 768 blocks are co-resident by construction: LDS 50176 B gives 3
// blocks/CU and __launch_bounds__(256,3) hard-caps VGPR at 168 (>= 3
// waves/SIMD), so grid 768 = 256 CU x 3 fits entirely.
// Agent-scope fences/atomics are cross-XCD coherent on gfx950.
__device__ __forceinline__ void gbar(unsigned* cnt, int t) {
  __threadfence();  // release this block's writes device-wide
  __syncthreads();
  if (t == 0) {
    __hip_atomic_fetch_add(cnt, 1u, __ATOMIC_ACQ_REL, __HIP_MEMORY_SCOPE_AGENT);
    while (__hip_atomic_load(cnt, __ATOMIC_ACQUIRE, __HIP_MEMORY_SCOPE_AGENT) < NBLK)
      __builtin_amdgcn_s_sleep(2);
  }
  __syncthreads();
  __threadfence();  // acquire: discard stale cached lines
}

// -----------------------------------------------------------------------------
// GEMM task (R9 panel-loop, verbatim): out = A(64x384 slab) @ Wt^T (+bias)*scale
// over NP=3 consecutive 64-col panels. A-frags in registers once; B restaged.
// -----------------------------------------------------------------------------
template <int OMODE>
__device__ __forceinline__ void pgemm_task(
    const unsigned short* __restrict__ A, const unsigned short* __restrict__ Bt,
    const float* __restrict__ bias, void* __restrict__ outp,
    int m0, int ng0, float scale, unsigned short (*Bs)[392]) {
  const int t = threadIdx.x;
  const int lane = t & 63, w = t >> 6, li = lane & 15, quad = lane >> 4;
  const int row = m0 + w * 16 + li;
  const int sr = t >> 2, scq = (t & 3) * 96;

#pragma unroll
  for (int i = 0; i < 12; ++i)
    *(short8*)&Bs[sr][scq + i * 8] =
        *(const short8*)(Bt + (size_t)(ng0 * 64 + sr) * 384 + scq + i * 8);

  short8 afr[12];
#pragma unroll
  for (int kk = 0; kk < 12; ++kk)
    afr[kk] = *(const short8*)(A + (size_t)row * 384 + kk * 32 + quad * 8);

#pragma unroll
  for (int pp = 0; pp < 3; ++pp) {
    __syncthreads();  // stage of panel pp visible
    v4f acc[4] = {};
#pragma unroll
    for (int kk = 0; kk < 12; ++kk) {
#pragma unroll
      for (int nt = 0; nt < 4; ++nt) {
        short8 bf = *(const short8*)&Bs[nt * 16 + li][kk * 32 + quad * 8];
        acc[nt] = __builtin_amdgcn_mfma_f32_16x16x32_bf16(afr[kk], bf, acc[nt], 0, 0, 0);
      }
    }
    __syncthreads();  // all Bs reads done; free for restage
    if (pp + 1 < 3) {
#pragma unroll
      for (int i = 0; i < 12; ++i)
        *(short8*)&Bs[sr][scq + i * 8] =
            *(const short8*)(Bt + (size_t)((ng0 + pp + 1) * 64 + sr) * 384 + scq + i * 8);
    }
    const int n0 = (ng0 + pp) * 64;
#pragma unroll
    for (int nt = 0; nt < 4; ++nt) {
      int col = n0 + nt * 16 + li;
      float bv = bias[col];
      int h = col >> 6, d = col & 63;
#pragma unroll
      for (int i = 0; i < 4; ++i) {
        int orow = m0 + w * 16 + quad * 4 + i;
        float val = (acc[nt][i] + bv) * scale;
        if constexpr (OMODE == OM_PLAIN) {
          ((float*)outp)[(size_t)orow * 384 + col] = val;
        } else if constexpr (OMODE == OM_Q || OMODE == OM_K) {
          int b = orow >> 10, n = orow & 1023;
          ((unsigned short*)outp)[((size_t)(b * 6 + h) << 16) + (n << 6) + d] = f2bf(val);
        } else if constexpr (OMODE == OM_VT) {
          int b = orow >> 10, n = orow & 1023;
          ((unsigned short*)outp)[((size_t)(b * 6 + h) << 16) + (d << 10) + n] = f2bf(val);
        } else {  // OM_PK / OM_PQ: [h][p][d]
          ((unsigned short*)outp)[(size_t)h * 49152 + (size_t)orow * 64 + d] = f2bf(val);
        }
      }
    }
  }
}

// -----------------------------------------------------------------------------
// Attention task — ROUND-8 KERNEL BODY VERBATIM (140.7 us, FETCH 14.6 MB):
// XCD working-set swizzle (validated) + T14 stage split on the ASTR=72
// LDS-band structure. Only change: LDS arrays carved from the shared smem.
// -----------------------------------------------------------------------------
#define ASTR 72

__device__ __forceinline__ void attn_task(
    int f, const unsigned short* __restrict__ q, const unsigned short* __restrict__ k,
    const unsigned short* __restrict__ vt, const unsigned short* __restrict__ pk,
    const unsigned short* __restrict__ pq, unsigned short* __restrict__ ao,
    unsigned short* smem) {
  unsigned short (*band1)[ASTR] = (unsigned short(*)[ASTR])smem;              // 128 rows
  unsigned short (*band2)[ASTR] = (unsigned short(*)[ASTR])(smem + 128 * ASTR);
  unsigned short (*Ps)[ASTR]    = (unsigned short(*)[ASTR])(smem + 256 * ASTR);

  const int g = f & 7, s = f >> 3;  // XCD working-set remap
  const int bh = g * 6 + (s >> 4);
  const int n0 = (s & 15) * 64;
  const int h = bh % 6, b = bh / 6;
  const int t = threadIdx.x;
  const int lane = t & 63, w = t >> 6;
  const int li = lane & 15, quad = lane >> 4;

  const unsigned short* qb = q + ((size_t)bh << 16);
  const unsigned short* kb = k + ((size_t)bh << 16);
  const unsigned short* vb = vt + ((size_t)bh << 16);
  const unsigned short* pkh = pk + (size_t)h * 49152;
  const unsigned short* pqh = pq + (size_t)h * 49152;

  short8 aq0 = *(const short8*)(qb + (size_t)(n0 + w * 16 + li) * 64 + quad * 8);
  short8 aq1 = *(const short8*)(qb + (size_t)(n0 + w * 16 + li) * 64 + 32 + quad * 8);

  float l_part[4] = {0.f, 0.f, 0.f, 0.f};
  v4f o[4] = {};

  const int sr = t >> 1, sc = (t & 1) * 32;
  short8 st1[4], st2[4];
  {
    int src = n0 - 0 - 63 + 384 + sr;
    src = src < 0 ? 0 : (src > 767 ? 767 : src);
    const unsigned short* p1 = pkh + (size_t)src * 64 + sc;
    const unsigned short* p2 = pqh + (size_t)src * 64 + sc;
#pragma unroll
    for (int ss = 0; ss < 4; ++ss) {
      st1[ss] = *(const short8*)(p1 + ss * 8);
      st2[ss] = *(const short8*)(p2 + ss * 8);
    }
  }

  for (int j0 = 0; j0 < 1024; j0 += 64) {
    __syncthreads();  // S0
#pragma unroll
    for (int ss = 0; ss < 4; ++ss) {
      *(short8*)&band1[sr][sc + ss * 8] = st1[ss];
      *(short8*)&band2[sr][sc + ss * 8] = st2[ss];
    }
    __syncthreads();  // S1

    {
      int src = n0 - (j0 + 64) - 63 + 384 + sr;
      src = src < 0 ? 0 : (src > 767 ? 767 : src);
      const unsigned short* p1 = pkh + (size_t)src * 64 + sc;
      const unsigned short* p2 = pqh + (size_t)src * 64 + sc;
#pragma unroll
      for (int ss = 0; ss < 4; ++ss) {
        st1[ss] = *(const short8*)(p1 + ss * 8);
        st2[ss] = *(const short8*)(p2 + ss * 8);
      }
    }

    short8 ak0 = *(const short8*)(kb + (size_t)(j0 + w * 16 + li) * 64 + quad * 8);
    short8 ak1 = *(const short8*)(kb + (size_t)(j0 + w * 16 + li) * 64 + 32 + quad * 8);

    v4f t1a[8] = {}, t2a[8] = {};
#pragma unroll
    for (int ct = 0; ct < 8; ++ct) {
      short8 b10 = *(const short8*)&band1[ct * 16 + li][quad * 8];
      short8 b11 = *(const short8*)&band1[ct * 16 + li][32 + quad * 8];
      t1a[ct] = __builtin_amdgcn_mfma_f32_16x16x32_bf16(aq0, b10, t1a[ct], 0, 0, 0);
      t1a[ct] = __builtin_amdgcn_mfma_f32_16x16x32_bf16(aq1, b11, t1a[ct], 0, 0, 0);
      short8 b20 = *(const short8*)&band2[ct * 16 + li][quad * 8];
      short8 b21 = *(const short8*)&band2[ct * 16 + li][32 + quad * 8];
      t2a[ct] = __builtin_amdgcn_mfma_f32_16x16x32_bf16(ak0, b20, t2a[ct], 0, 0, 0);
      t2a[ct] = __builtin_amdgcn_mfma_f32_16x16x32_bf16(ak1, b21, t2a[ct], 0, 0, 0);
    }
    __syncthreads();  // S2

#pragma unroll
    for (int ct = 0; ct < 8; ++ct) {
      us4 p1 = {f2bf(t1a[ct][0]), f2bf(t1a[ct][1]), f2bf(t1a[ct][2]), f2bf(t1a[ct][3])};
      us4 p2 = {f2bf(t2a[ct][0]), f2bf(t2a[ct][1]), f2bf(t2a[ct][2]), f2bf(t2a[ct][3])};
      *(us4*)&band1[ct * 16 + li][w * 16 + quad * 4] = p1;
      *(us4*)&band2[ct * 16 + li][w * 16 + quad * 4] = p2;
    }
    v4f sqk[4] = {};
#pragma unroll
    for (int nt = 0; nt < 4; ++nt) {
      short8 b0 = *(const short8*)(kb + (size_t)(j0 + nt * 16 + li) * 64 + quad * 8);
      short8 b1 = *(const short8*)(kb + (size_t)(j0 + nt * 16 + li) * 64 + 32 + quad * 8);
      sqk[nt] = __builtin_amdgcn_mfma_f32_16x16x32_bf16(aq0, b0, sqk[nt], 0, 0, 0);
      sqk[nt] = __builtin_amdgcn_mfma_f32_16x16x32_bf16(aq1, b1, sqk[nt], 0, 0, 0);
    }
    __syncthreads();  // S3

#pragma unroll
    for (int nt = 0; nt < 4; ++nt) {
      int jl = nt * 16 + li;
#pragma unroll
      for (int i = 0; i < 4; ++i) {
        int nl = w * 16 + quad * 4 + i;
        int r = nl - jl + 63;
        float s2 = sqk[nt][i] + bf2f(band1[r][nl]) + bf2f(band2[r][jl]);
        float p = __expf(s2);
        l_part[i] += p;
        Ps[nl][jl] = f2bf(p);
      }
    }
#pragma unroll
    for (int kst = 0; kst < 2; ++kst) {
      short8 ap = *(const short8*)&Ps[w * 16 + li][kst * 32 + quad * 8];
#pragma unroll
      for (int nt = 0; nt < 4; ++nt) {
        short8 bv2 = *(const short8*)(vb + (size_t)(nt * 16 + li) * 1024 + j0 + kst * 32 + quad * 8);
        o[nt] = __builtin_amdgcn_mfma_f32_16x16x32_bf16(ap, bv2, o[nt], 0, 0, 0);
      }
    }
  }

#pragma unroll
  for (int i = 0; i < 4; ++i) {
    float l = l_part[i];
    l += __shfl_xor(l, 1);
    l += __shfl_xor(l, 2);
    l += __shfl_xor(l, 4);
    l += __shfl_xor(l, 8);
    float inv_l = 1.f / l;
    int nl = w * 16 + quad * 4 + i;
#pragma unroll
    for (int nt = 0; nt < 4; ++nt)
      ao[((size_t)(b * 1024 + n0 + nl)) * 384 + h * 64 + nt * 16 + li] =
          f2bf(o[nt][i] * inv_l);
  }
}

// -----------------------------------------------------------------------------
// ROUND-10 RESUBMIT (R10 aborted on a fresh/sick container — preloaded=0.0,
// 46-68 s npz pushes, fast pytest abort: same signature as R3's proven infra
// flake; static audit of barrier/co-residency/task-coverage found no fault.
// Decision rule: a second identical abort implicates the fused structure ->
// revert to R9 baseline next round.)
//
// ONE fused kernel, 4 phases, manual grid barriers. Diagnosis: non-attn
// "rest" is ~121-131 us across ALL rounds while ideal GPU-busy is ~16 us
// => ~25 us per kernel boundary, invariant to kernel internals (R9 cut
// 190 MB of traffic, recovered only 10 us). Fusing 5 launches -> 1 deletes
// 4 boundaries. Phases:
//  P0 prep: x/re -> bf16 (all blocks) + 6 weight transposes (blocks 0..215)
//  P1 proj: 816 GEMM tasks (q/k/v: 768; pk/pq: blocks 0..47 take a 2nd task)
//  P2 attn: R8 body verbatim (XCD remap expects flat id 0..767)
//  P3 out:  256 GEMM tasks (blocks 0..255)
// -----------------------------------------------------------------------------
__global__ __launch_bounds__(256, 3) void fused_all(
    const float* __restrict__ x, const float* __restrict__ re,
    const float* __restrict__ Wq, const float* __restrict__ bq,
    const float* __restrict__ Wk, const float* __restrict__ bk,
    const float* __restrict__ Wv, const float* __restrict__ bv,
    const float* __restrict__ Wpk, const float* __restrict__ bpk,
    const float* __restrict__ Wpq, const float* __restrict__ bpq,
    const float* __restrict__ Wo, const float* __restrict__ bo,
    float* __restrict__ out, unsigned short* __restrict__ ws,
    unsigned* __restrict__ cnt) {
  __shared__ __align__(16) unsigned short smem[25088];  // 50176 B, union of phases

  unsigned short* Wt  = ws;                 // 6*384*384
  unsigned short* qw  = Wt + 884736;        // (B,H,N,D) bf16, pre-scaled
  unsigned short* kw  = qw + 3145728;
  unsigned short* vtw = kw + 3145728;       // (B,H,D,N)
  unsigned short* pkw = vtw + 3145728;      // [h][p][d]
  unsigned short* pqw = pkw + 294912;       // pre-scaled
  unsigned short* aow = pqw + 294912;       // 8192*384 bf16
  unsigned short* xb  = aow + 3145728;      // 8192*384 bf16
  unsigned short* reb = xb + 3145728;       // 768*384 bf16

  const int f = blockIdx.x;
  const int t = threadIdx.x;

  // ---------------- P0: prep ----------------
  {  // x -> bf16: 16 elems/thread; 768*256*16 = 3145728 exactly
    size_t idx = ((size_t)f * 256 + t) * 16;
    float4 u0 = *(const float4*)(x + idx);
    float4 u1 = *(const float4*)(x + idx + 4);
    float4 u2 = *(const float4*)(x + idx + 8);
    float4 u3 = *(const float4*)(x + idx + 12);
    short8 v0, v1;
    v0[0] = (short)f2bf(u0.x); v0[1] = (short)f2bf(u0.y);
    v0[2] = (short)f2bf(u0.z); v0[3] = (short)f2bf(u0.w);
    v0[4] = (short)f2bf(u1.x); v0[5] = (short)f2bf(u1.y);
    v0[6] = (short)f2bf(u1.z); v0[7] = (short)f2bf(u1.w);
    v1[0] = (short)f2bf(u2.x); v1[1] = (short)f2bf(u2.y);
    v1[2] = (short)f2bf(u2.z); v1[3] = (short)f2bf(u2.w);
    v1[4] = (short)f2bf(u3.x); v1[5] = (short)f2bf(u3.y);
    v1[6] = (short)f2bf(u3.z); v1[7] = (short)f2bf(u3.w);
    *(short8*)(xb + idx) = v0;
    *(short8*)(xb + idx + 8) = v1;
  }
  if (f >= 216 && f < 360) {  // re -> bf16: 144*256*8 = 294912 exactly
    size_t r = ((size_t)(f - 216) * 256 + t) * 8;
    float4 u0 = *(const float4*)(re + r);
    float4 u1 = *(const float4*)(re + r + 4);
    short8 v;
    v[0] = (short)f2bf(u0.x); v[1] = (short)f2bf(u0.y);
    v[2] = (short)f2bf(u0.z); v[3] = (short)f2bf(u0.w);
    v[4] = (short)f2bf(u1.x); v[5] = (short)f2bf(u1.y);
    v[6] = (short)f2bf(u1.z); v[7] = (short)f2bf(u1.w);
    *(short8*)(reb + r) = v;
  }
  if (f < 216) {  // weight transpose: 6 mats x 36 tiles
    const int mat = f / 36, rem = f % 36;
    const float* W = mat == 0 ? Wq : mat == 1 ? Wk : mat == 2 ? Wv
                   : mat == 3 ? Wpk : mat == 4 ? Wpq : Wo;
    const int tk = (rem % 6) * 64, tn = (rem / 6) * 64;
    unsigned short (*Ts)[68] = (unsigned short(*)[68])smem;
#pragma unroll
    for (int it = 0; it < 4; ++it) {
      int r = (t >> 4) + it * 16, c = (t & 15) * 4;
      float4 v = *(const float4*)(W + (size_t)(tk + r) * 384 + tn + c);
      us4 p = {f2bf(v.x), f2bf(v.y), f2bf(v.z), f2bf(v.w)};
      *(us4*)&Ts[r][c] = p;
    }
    __syncthreads();
    unsigned short* outp = Wt + (size_t)mat * 147456;
#pragma unroll
    for (int it = 0; it < 2; ++it) {
      int n = (t >> 3) + it * 32, kc = (t & 7) * 8;
      unsigned short tmp[8];
#pragma unroll
      for (int j = 0; j < 8; ++j) tmp[j] = Ts[kc + j][n];
      *(short8*)(outp + (size_t)(tn + n) * 384 + tk + kc) = *(short8*)tmp;
    }
  }
  gbar(cnt + 0, t);

  // ---------------- P1: projections (816 tasks) ----------------
  {
    unsigned short (*Bs)[392] = (unsigned short(*)[392])smem;
    const int which = f / 256, r = f & 255;
    const int m0 = (r >> 1) * 64, ng0 = (r & 1) * 3;
    switch (which) {
      case 0:  pgemm_task<OM_Q >(xb, Wt,              bq, qw,  m0, ng0, INV_SCALE, Bs); break;
      case 1:  pgemm_task<OM_K >(xb, Wt + 147456,     bk, kw,  m0, ng0, 1.f, Bs); break;
      default: pgemm_task<OM_VT>(xb, Wt + 2 * 147456, bv, vtw, m0, ng0, 1.f, Bs); break;
    }
    if (f < 48) {  // pk/pq: 2 mats x 12 mblocks x 2 groups
      const int u = f % 24;
      const int m2 = (u >> 1) * 64, ng2 = (u & 1) * 3;
      if (f < 24) pgemm_task<OM_PK>(reb, Wt + 3 * 147456, bpk, pkw, m2, ng2, 1.f, Bs);
      else        pgemm_task<OM_PQ>(reb, Wt + 4 * 147456, bpq, pqw, m2, ng2, INV_SCALE, Bs);
    }
  }
  gbar(cnt + 1, t);

  // ---------------- P2: attention ----------------
  attn_task(f, qw, kw, vtw, pkw, pqw, aow, smem);
  gbar(cnt + 2, t);

  // ---------------- P3: output GEMM (256 tasks) ----------------
  if (f < 256) {
    unsigned short (*Bs)[392] = (unsigned short(*)[392])smem;
    pgemm_task<OM_PLAIN>(aow, Wt + 5 * 147456, bo, out,
                         (f >> 1) * 64, (f & 1) * 3, 1.f, Bs);
  }
}

// -----------------------------------------------------------------------------
extern "C" void kernel_launch(void* const* d_in, const int* in_sizes, int n_in,
                              void* d_out, int out_size, void* d_ws,
                              size_t ws_size, hipStream_t stream) {
  const float* x   = (const float*)d_in[0];
  const float* re  = (const float*)d_in[2];
  const float* Wq  = (const float*)d_in[3];
  const float* bq  = (const float*)d_in[4];
  const float* Wk  = (const float*)d_in[5];
  const float* bk  = (const float*)d_in[6];
  const float* Wv  = (const float*)d_in[7];
  const float* bv  = (const float*)d_in[8];
  const float* Wpk = (const float*)d_in[9];
  const float* bpk = (const float*)d_in[10];
  const float* Wpq = (const float*)d_in[11];
  const float* bpq = (const float*)d_in[12];
  const float* Wo  = (const float*)d_in[13];
  const float* bo  = (const float*)d_in[14];
  float* out = (float*)d_out;

  unsigned short* ws = (unsigned short*)d_ws;
  // barrier counters live just past the last workspace buffer (~35 MB used,
  // >= 53 MB proven available); zeroed every launch (graph-capturable).
  unsigned* cnt = (unsigned*)(ws + 884736 + 3 * 3145728 + 2 * 294912 +
                              3145728 + 3145728 + 294912);
  hipMemsetAsync(cnt, 0, 16, stream);
  fused_all<<<dim3(NBLK), dim3(256), 0, stream>>>(
      x, re, Wq, bq, Wk, bk, Wv, bv, Wpk, bpk, Wpq, bpq, Wo, bo,
      out, ws, cnt);
}

// Round 14
// 799.933 us; speedup vs baseline: 1.2281x; 1.2281x over previous
//
#include <hip/hip_runtime.h>
#include <math.h>

typedef __attribute__((ext_vector_type(8))) short short8;
typedef __attribute__((ext_vector_type(4))) float v4f;
typedef __attribute__((ext_vector_type(4))) unsigned short us4;

#define INV_SCALE 0.07216878364870322f  // 1/sqrt(64*3)
#define NBLK 768u

__device__ __forceinline__ unsigned short f2bf(float f) {
  unsigned u = __builtin_bit_cast(unsigned, f);
  u = (u + 0x7FFFu + ((u >> 16) & 1u)) >> 16;  // RNE
  return (unsigned short)u;
}
__device__ __forceinline__ float bf2f(unsigned short h) {
  unsigned u = ((unsigned)h) << 16;
  return __builtin_bit_cast(float, u);
}

enum { OM_PLAIN = 0, OM_Q = 1, OM_K = 2, OM_VT = 3, OM_PK = 4, OM_PQ = 5 };

// Device-scope grid barrier — R12 FIX: poll with RELAXED ordering.
// R11's poll used ACQUIRE at agent scope, which on gfx950 invalidates the
// XCD's L1/L2 EVERY POLL ITERATION (768 spinners x ~every 130 cyc for the
// whole skew window of every barrier) -> all-miss latency starvation:
// 915 us, MfmaUtil 2.1%, all pipes idle. Fix: relaxed poll (plain coherent
// load, no invalidate); the ONE acquire (post-loop __threadfence) provides
// the needed stale-line discard. Release unchanged (one wbl2 per block).
// Co-residency proof unchanged: LDS 50176 B -> 3 blocks/CU; launch_bounds
// (256,3) caps VGPR <= 168; grid 768 = 256 CU x 3 exactly.
__device__ __forceinline__ void gbar(unsigned* cnt, int t) {
  __threadfence();  // release this block's writes device-wide
  __syncthreads();
  if (t == 0) {
    __hip_atomic_fetch_add(cnt, 1u, __ATOMIC_RELAXED, __HIP_MEMORY_SCOPE_AGENT);
    while (__hip_atomic_load(cnt, __ATOMIC_RELAXED, __HIP_MEMORY_SCOPE_AGENT) < NBLK)
      __builtin_amdgcn_s_sleep(8);
  }
  __syncthreads();
  __threadfence();  // single acquire: discard stale cached lines once
}

// -----------------------------------------------------------------------------
// GEMM task (R9 panel-loop, verbatim): out = A(64x384 slab) @ Wt^T (+bias)*scale
// over NP=3 consecutive 64-col panels. A-frags in registers once; B restaged.
// -----------------------------------------------------------------------------
template <int OMODE>
__device__ __forceinline__ void pgemm_task(
    const unsigned short* __restrict__ A, const unsigned short* __restrict__ Bt,
    const float* __restrict__ bias, void* __restrict__ outp,
    int m0, int ng0, float scale, unsigned short (*Bs)[392]) {
  const int t = threadIdx.x;
  const int lane = t & 63, w = t >> 6, li = lane & 15, quad = lane >> 4;
  const int row = m0 + w * 16 + li;
  const int sr = t >> 2, scq = (t & 3) * 96;

#pragma unroll
  for (int i = 0; i < 12; ++i)
    *(short8*)&Bs[sr][scq + i * 8] =
        *(const short8*)(Bt + (size_t)(ng0 * 64 + sr) * 384 + scq + i * 8);

  short8 afr[12];
#pragma unroll
  for (int kk = 0; kk < 12; ++kk)
    afr[kk] = *(const short8*)(A + (size_t)row * 384 + kk * 32 + quad * 8);

#pragma unroll
  for (int pp = 0; pp < 3; ++pp) {
    __syncthreads();  // stage of panel pp visible
    v4f acc[4] = {};
#pragma unroll
    for (int kk = 0; kk < 12; ++kk) {
#pragma unroll
      for (int nt = 0; nt < 4; ++nt) {
        short8 bf = *(const short8*)&Bs[nt * 16 + li][kk * 32 + quad * 8];
        acc[nt] = __builtin_amdgcn_mfma_f32_16x16x32_bf16(afr[kk], bf, acc[nt], 0, 0, 0);
      }
    }
    __syncthreads();  // all Bs reads done; free for restage
    if (pp + 1 < 3) {
#pragma unroll
      for (int i = 0; i < 12; ++i)
        *(short8*)&Bs[sr][scq + i * 8] =
            *(const short8*)(Bt + (size_t)((ng0 + pp + 1) * 64 + sr) * 384 + scq + i * 8);
    }
    const int n0 = (ng0 + pp) * 64;
#pragma unroll
    for (int nt = 0; nt < 4; ++nt) {
      int col = n0 + nt * 16 + li;
      float bv = bias[col];
      int h = col >> 6, d = col & 63;
#pragma unroll
      for (int i = 0; i < 4; ++i) {
        int orow = m0 + w * 16 + quad * 4 + i;
        float val = (acc[nt][i] + bv) * scale;
        if constexpr (OMODE == OM_PLAIN) {
          ((float*)outp)[(size_t)orow * 384 + col] = val;
        } else if constexpr (OMODE == OM_Q || OMODE == OM_K) {
          int b = orow >> 10, n = orow & 1023;
          ((unsigned short*)outp)[((size_t)(b * 6 + h) << 16) + (n << 6) + d] = f2bf(val);
        } else if constexpr (OMODE == OM_VT) {
          int b = orow >> 10, n = orow & 1023;
          ((unsigned short*)outp)[((size_t)(b * 6 + h) << 16) + (d << 10) + n] = f2bf(val);
        } else {  // OM_PK / OM_PQ: [h][p][d]
          ((unsigned short*)outp)[(size_t)h * 49152 + (size_t)orow * 64 + d] = f2bf(val);
        }
      }
    }
  }
}

// -----------------------------------------------------------------------------
// Attention task — ROUND-8 KERNEL BODY VERBATIM (140.7 us, FETCH 14.6 MB):
// XCD working-set swizzle (validated) + T14 stage split on the ASTR=72
// LDS-band structure. Only change: LDS arrays carved from the shared smem.
// -----------------------------------------------------------------------------
#define ASTR 72

__device__ __forceinline__ void attn_task(
    int f, const unsigned short* __restrict__ q, const unsigned short* __restrict__ k,
    const unsigned short* __restrict__ vt, const unsigned short* __restrict__ pk,
    const unsigned short* __restrict__ pq, unsigned short* __restrict__ ao,
    unsigned short* smem) {
  unsigned short (*band1)[ASTR] = (unsigned short(*)[ASTR])smem;              // 128 rows
  unsigned short (*band2)[ASTR] = (unsigned short(*)[ASTR])(smem + 128 * ASTR);
  unsigned short (*Ps)[ASTR]    = (unsigned short(*)[ASTR])(smem + 256 * ASTR);

  const int g = f & 7, s = f >> 3;  // XCD working-set remap
  const int bh = g * 6 + (s >> 4);
  const int n0 = (s & 15) * 64;
  const int h = bh % 6, b = bh / 6;
  const int t = threadIdx.x;
  const int lane = t & 63, w = t >> 6;
  const int li = lane & 15, quad = lane >> 4;

  const unsigned short* qb = q + ((size_t)bh << 16);
  const unsigned short* kb = k + ((size_t)bh << 16);
  const unsigned short* vb = vt + ((size_t)bh << 16);
  const unsigned short* pkh = pk + (size_t)h * 49152;
  const unsigned short* pqh = pq + (size_t)h * 49152;

  short8 aq0 = *(const short8*)(qb + (size_t)(n0 + w * 16 + li) * 64 + quad * 8);
  short8 aq1 = *(const short8*)(qb + (size_t)(n0 + w * 16 + li) * 64 + 32 + quad * 8);

  float l_part[4] = {0.f, 0.f, 0.f, 0.f};
  v4f o[4] = {};

  const int sr = t >> 1, sc = (t & 1) * 32;
  short8 st1[4], st2[4];
  {
    int src = n0 - 0 - 63 + 384 + sr;
    src = src < 0 ? 0 : (src > 767 ? 767 : src);
    const unsigned short* p1 = pkh + (size_t)src * 64 + sc;
    const unsigned short* p2 = pqh + (size_t)src * 64 + sc;
#pragma unroll
    for (int ss = 0; ss < 4; ++ss) {
      st1[ss] = *(const short8*)(p1 + ss * 8);
      st2[ss] = *(const short8*)(p2 + ss * 8);
    }
  }

  for (int j0 = 0; j0 < 1024; j0 += 64) {
    __syncthreads();  // S0
#pragma unroll
    for (int ss = 0; ss < 4; ++ss) {
      *(short8*)&band1[sr][sc + ss * 8] = st1[ss];
      *(short8*)&band2[sr][sc + ss * 8] = st2[ss];
    }
    __syncthreads();  // S1

    {
      int src = n0 - (j0 + 64) - 63 + 384 + sr;
      src = src < 0 ? 0 : (src > 767 ? 767 : src);
      const unsigned short* p1 = pkh + (size_t)src * 64 + sc;
      const unsigned short* p2 = pqh + (size_t)src * 64 + sc;
#pragma unroll
      for (int ss = 0; ss < 4; ++ss) {
        st1[ss] = *(const short8*)(p1 + ss * 8);
        st2[ss] = *(const short8*)(p2 + ss * 8);
      }
    }

    short8 ak0 = *(const short8*)(kb + (size_t)(j0 + w * 16 + li) * 64 + quad * 8);
    short8 ak1 = *(const short8*)(kb + (size_t)(j0 + w * 16 + li) * 64 + 32 + quad * 8);

    v4f t1a[8] = {}, t2a[8] = {};
#pragma unroll
    for (int ct = 0; ct < 8; ++ct) {
      short8 b10 = *(const short8*)&band1[ct * 16 + li][quad * 8];
      short8 b11 = *(const short8*)&band1[ct * 16 + li][32 + quad * 8];
      t1a[ct] = __builtin_amdgcn_mfma_f32_16x16x32_bf16(aq0, b10, t1a[ct], 0, 0, 0);
      t1a[ct] = __builtin_amdgcn_mfma_f32_16x16x32_bf16(aq1, b11, t1a[ct], 0, 0, 0);
      short8 b20 = *(const short8*)&band2[ct * 16 + li][quad * 8];
      short8 b21 = *(const short8*)&band2[ct * 16 + li][32 + quad * 8];
      t2a[ct] = __builtin_amdgcn_mfma_f32_16x16x32_bf16(ak0, b20, t2a[ct], 0, 0, 0);
      t2a[ct] = __builtin_amdgcn_mfma_f32_16x16x32_bf16(ak1, b21, t2a[ct], 0, 0, 0);
    }
    __syncthreads();  // S2

#pragma unroll
    for (int ct = 0; ct < 8; ++ct) {
      us4 p1 = {f2bf(t1a[ct][0]), f2bf(t1a[ct][1]), f2bf(t1a[ct][2]), f2bf(t1a[ct][3])};
      us4 p2 = {f2bf(t2a[ct][0]), f2bf(t2a[ct][1]), f2bf(t2a[ct][2]), f2bf(t2a[ct][3])};
      *(us4*)&band1[ct * 16 + li][w * 16 + quad * 4] = p1;
      *(us4*)&band2[ct * 16 + li][w * 16 + quad * 4] = p2;
    }
    v4f sqk[4] = {};
#pragma unroll
    for (int nt = 0; nt < 4; ++nt) {
      short8 b0 = *(const short8*)(kb + (size_t)(j0 + nt * 16 + li) * 64 + quad * 8);
      short8 b1 = *(const short8*)(kb + (size_t)(j0 + nt * 16 + li) * 64 + 32 + quad * 8);
      sqk[nt] = __builtin_amdgcn_mfma_f32_16x16x32_bf16(aq0, b0, sqk[nt], 0, 0, 0);
      sqk[nt] = __builtin_amdgcn_mfma_f32_16x16x32_bf16(aq1, b1, sqk[nt], 0, 0, 0);
    }
    __syncthreads();  // S3

#pragma unroll
    for (int nt = 0; nt < 4; ++nt) {
      int jl = nt * 16 + li;
#pragma unroll
      for (int i = 0; i < 4; ++i) {
        int nl = w * 16 + quad * 4 + i;
        int r = nl - jl + 63;
        float s2 = sqk[nt][i] + bf2f(band1[r][nl]) + bf2f(band2[r][jl]);
        float p = __expf(s2);
        l_part[i] += p;
        Ps[nl][jl] = f2bf(p);
      }
    }
#pragma unroll
    for (int kst = 0; kst < 2; ++kst) {
      short8 ap = *(const short8*)&Ps[w * 16 + li][kst * 32 + quad * 8];
#pragma unroll
      for (int nt = 0; nt < 4; ++nt) {
        short8 bv2 = *(const short8*)(vb + (size_t)(nt * 16 + li) * 1024 + j0 + kst * 32 + quad * 8);
        o[nt] = __builtin_amdgcn_mfma_f32_16x16x32_bf16(ap, bv2, o[nt], 0, 0, 0);
      }
    }
  }

#pragma unroll
  for (int i = 0; i < 4; ++i) {
    float l = l_part[i];
    l += __shfl_xor(l, 1);
    l += __shfl_xor(l, 2);
    l += __shfl_xor(l, 4);
    l += __shfl_xor(l, 8);
    float inv_l = 1.f / l;
    int nl = w * 16 + quad * 4 + i;
#pragma unroll
    for (int nt = 0; nt < 4; ++nt)
      ao[((size_t)(b * 1024 + n0 + nl)) * 384 + h * 64 + nt * 16 + li] =
          f2bf(o[nt][i] * inv_l);
  }
}

// -----------------------------------------------------------------------------
// ROUND-12 RESUBMIT x2 (R12/R13 were broker timeouts; the relaxed-poll fix
// has never run). R11 fused structure BYTE-IDENTICAL except the gbar memory
// orderings (ACQUIRE-poll -> RELAXED-poll + single post-loop acquire) and
// s_sleep 2 -> 8. Single-variable A/B vs R11's 915 us.
//  P0 prep: x/re -> bf16 (all blocks) + 6 weight transposes (blocks 0..215)
//  P1 proj: 816 GEMM tasks (q/k/v: 768; pk/pq: blocks 0..47 take a 2nd task)
//  P2 attn: R8 body verbatim (XCD remap expects flat id 0..767)
//  P3 out:  256 GEMM tasks (blocks 0..255)
// Pre-committed: if dur >= 260 us (R9 baseline), fused approach is abandoned
// next round.
// -----------------------------------------------------------------------------
__global__ __launch_bounds__(256, 3) void fused_all(
    const float* __restrict__ x, const float* __restrict__ re,
    const float* __restrict__ Wq, const float* __restrict__ bq,
    const float* __restrict__ Wk, const float* __restrict__ bk,
    const float* __restrict__ Wv, const float* __restrict__ bv,
    const float* __restrict__ Wpk, const float* __restrict__ bpk,
    const float* __restrict__ Wpq, const float* __restrict__ bpq,
    const float* __restrict__ Wo, const float* __restrict__ bo,
    float* __restrict__ out, unsigned short* __restrict__ ws,
    unsigned* __restrict__ cnt) {
  __shared__ __align__(16) unsigned short smem[25088];  // 50176 B, union of phases

  unsigned short* Wt  = ws;                 // 6*384*384
  unsigned short* qw  = Wt + 884736;        // (B,H,N,D) bf16, pre-scaled
  unsigned short* kw  = qw + 3145728;
  unsigned short* vtw = kw + 3145728;       // (B,H,D,N)
  unsigned short* pkw = vtw + 3145728;      // [h][p][d]
  unsigned short* pqw = pkw + 294912;       // pre-scaled
  unsigned short* aow = pqw + 294912;       // 8192*384 bf16
  unsigned short* xb  = aow + 3145728;      // 8192*384 bf16
  unsigned short* reb = xb + 3145728;       // 768*384 bf16

  const int f = blockIdx.x;
  const int t = threadIdx.x;

  // ---------------- P0: prep ----------------
  {  // x -> bf16: 16 elems/thread; 768*256*16 = 3145728 exactly
    size_t idx = ((size_t)f * 256 + t) * 16;
    float4 u0 = *(const float4*)(x + idx);
    float4 u1 = *(const float4*)(x + idx + 4);
    float4 u2 = *(const float4*)(x + idx + 8);
    float4 u3 = *(const float4*)(x + idx + 12);
    short8 v0, v1;
    v0[0] = (short)f2bf(u0.x); v0[1] = (short)f2bf(u0.y);
    v0[2] = (short)f2bf(u0.z); v0[3] = (short)f2bf(u0.w);
    v0[4] = (short)f2bf(u1.x); v0[5] = (short)f2bf(u1.y);
    v0[6] = (short)f2bf(u1.z); v0[7] = (short)f2bf(u1.w);
    v1[0] = (short)f2bf(u2.x); v1[1] = (short)f2bf(u2.y);
    v1[2] = (short)f2bf(u2.z); v1[3] = (short)f2bf(u2.w);
    v1[4] = (short)f2bf(u3.x); v1[5] = (short)f2bf(u3.y);
    v1[6] = (short)f2bf(u3.z); v1[7] = (short)f2bf(u3.w);
    *(short8*)(xb + idx) = v0;
    *(short8*)(xb + idx + 8) = v1;
  }
  if (f >= 216 && f < 360) {  // re -> bf16: 144*256*8 = 294912 exactly
    size_t r = ((size_t)(f - 216) * 256 + t) * 8;
    float4 u0 = *(const float4*)(re + r);
    float4 u1 = *(const float4*)(re + r + 4);
    short8 v;
    v[0] = (short)f2bf(u0.x); v[1] = (short)f2bf(u0.y);
    v[2] = (short)f2bf(u0.z); v[3] = (short)f2bf(u0.w);
    v[4] = (short)f2bf(u1.x); v[5] = (short)f2bf(u1.y);
    v[6] = (short)f2bf(u1.z); v[7] = (short)f2bf(u1.w);
    *(short8*)(reb + r) = v;
  }
  if (f < 216) {  // weight transpose: 6 mats x 36 tiles
    const int mat = f / 36, rem = f % 36;
    const float* W = mat == 0 ? Wq : mat == 1 ? Wk : mat == 2 ? Wv
                   : mat == 3 ? Wpk : mat == 4 ? Wpq : Wo;
    const int tk = (rem % 6) * 64, tn = (rem / 6) * 64;
    unsigned short (*Ts)[68] = (unsigned short(*)[68])smem;
#pragma unroll
    for (int it = 0; it < 4; ++it) {
      int r = (t >> 4) + it * 16, c = (t & 15) * 4;
      float4 v = *(const float4*)(W + (size_t)(tk + r) * 384 + tn + c);
      us4 p = {f2bf(v.x), f2bf(v.y), f2bf(v.z), f2bf(v.w)};
      *(us4*)&Ts[r][c] = p;
    }
    __syncthreads();
    unsigned short* outp = Wt + (size_t)mat * 147456;
#pragma unroll
    for (int it = 0; it < 2; ++it) {
      int n = (t >> 3) + it * 32, kc = (t & 7) * 8;
      unsigned short tmp[8];
#pragma unroll
      for (int j = 0; j < 8; ++j) tmp[j] = Ts[kc + j][n];
      *(short8*)(outp + (size_t)(tn + n) * 384 + tk + kc) = *(short8*)tmp;
    }
  }
  gbar(cnt + 0, t);

  // ---------------- P1: projections (816 tasks) ----------------
  {
    unsigned short (*Bs)[392] = (unsigned short(*)[392])smem;
    const int which = f / 256, r = f & 255;
    const int m0 = (r >> 1) * 64, ng0 = (r & 1) * 3;
    switch (which) {
      case 0:  pgemm_task<OM_Q >(xb, Wt,              bq, qw,  m0, ng0, INV_SCALE, Bs); break;
      case 1:  pgemm_task<OM_K >(xb, Wt + 147456,     bk, kw,  m0, ng0, 1.f, Bs); break;
      default: pgemm_task<OM_VT>(xb, Wt + 2 * 147456, bv, vtw, m0, ng0, 1.f, Bs); break;
    }
    if (f < 48) {  // pk/pq: 2 mats x 12 mblocks x 2 groups
      const int u = f % 24;
      const int m2 = (u >> 1) * 64, ng2 = (u & 1) * 3;
      if (f < 24) pgemm_task<OM_PK>(reb, Wt + 3 * 147456, bpk, pkw, m2, ng2, 1.f, Bs);
      else        pgemm_task<OM_PQ>(reb, Wt + 4 * 147456, bpq, pqw, m2, ng2, INV_SCALE, Bs);
    }
  }
  gbar(cnt + 1, t);

  // ---------------- P2: attention ----------------
  attn_task(f, qw, kw, vtw, pkw, pqw, aow, smem);
  gbar(cnt + 2, t);

  // ---------------- P3: output GEMM (256 tasks) ----------------
  if (f < 256) {
    unsigned short (*Bs)[392] = (unsigned short(*)[392])smem;
    pgemm_task<OM_PLAIN>(aow, Wt + 5 * 147456, bo, out,
                         (f >> 1) * 64, (f & 1) * 3, 1.f, Bs);
  }
}

// -----------------------------------------------------------------------------
extern "C" void kernel_launch(void* const* d_in, const int* in_sizes, int n_in,
                              void* d_out, int out_size, void* d_ws,
                              size_t ws_size, hipStream_t stream) {
  const float* x   = (const float*)d_in[0];
  const float* re  = (const float*)d_in[2];
  const float* Wq  = (const float*)d_in[3];
  const float* bq  = (const float*)d_in[4];
  const float* Wk  = (const float*)d_in[5];
  const float* bk  = (const float*)d_in[6];
  const float* Wv  = (const float*)d_in[7];
  const float* bv  = (const float*)d_in[8];
  const float* Wpk = (const float*)d_in[9];
  const float* bpk = (const float*)d_in[10];
  const float* Wpq = (const float*)d_in[11];
  const float* bpq = (const float*)d_in[12];
  const float* Wo  = (const float*)d_in[13];
  const float* bo  = (const float*)d_in[14];
  float* out = (float*)d_out;

  unsigned short* ws = (unsigned short*)d_ws;
  // barrier counters live just past the last workspace buffer (~35 MB used,
  // >= 53 MB proven available); zeroed every launch (graph-capturable).
  unsigned* cnt = (unsigned*)(ws + 884736 + 3 * 3145728 + 2 * 294912 +
                              3145728 + 3145728 + 294912);
  hipMemsetAsync(cnt, 0, 16, stream);
  fused_all<<<dim3(NBLK), dim3(256), 0, stream>>>(
      x, re, Wq, bq, Wk, bk, Wv, bv, Wpk, bpk, Wpq, bpq, Wo, bo,
      out, ws, cnt);
}

// Round 16
// 257.323 us; speedup vs baseline: 3.8178x; 3.1087x over previous
//
#include <hip/hip_runtime.h>
#include <math.h>

typedef __attribute__((ext_vector_type(8))) short short8;
typedef __attribute__((ext_vector_type(4))) float v4f;
typedef __attribute__((ext_vector_type(4))) unsigned short us4;

#define INV_SCALE 0.07216878364870322f  // 1/sqrt(64*3)

__device__ __forceinline__ unsigned short f2bf(float f) {
  unsigned u = __builtin_bit_cast(unsigned, f);
  u = (u + 0x7FFFu + ((u >> 16) & 1u)) >> 16;  // RNE
  return (unsigned short)u;
}
__device__ __forceinline__ float bf2f(unsigned short h) {
  unsigned u = ((unsigned)h) << 16;
  return __builtin_bit_cast(float, u);
}

enum { OM_PLAIN = 0, OM_Q = 1, OM_K = 2, OM_VT = 3, OM_PK = 4, OM_PQ = 5 };

// -----------------------------------------------------------------------------
// ROUND-15 RESUBMIT (R15 was a broker timeout; kernel never ran).
// REVERT to the R9 five-kernel structure (best measured 260.4 us).
// Fused-single-kernel approach abandoned per pre-committed gate: R11=915,
// R14(relaxed-poll)=718 us — device-scope grid barriers on non-coherent-XCD
// gfx950 (768x wbl2 release + 768x inv acquire per barrier, destroying all
// warm cache state between phases) cost far more than 4 kernel boundaries.
// One change vs R9: cvt_bf16 + transpose_w merged into ONE prep_all dispatch
// (independent work, 5 launches -> 4; transpose hides under cvt's traffic).
// -----------------------------------------------------------------------------
// prep_all grid: 1896 blocks. bid < 1680: x/re -> bf16 (8 elems/thread).
// bid >= 1680: weight transpose tile (6 mats x 36 tiles).
__global__ __launch_bounds__(256) void prep_all(
    const float* __restrict__ x, const float* __restrict__ re,
    const float* __restrict__ Wq, const float* __restrict__ Wk,
    const float* __restrict__ Wv, const float* __restrict__ Wpk,
    const float* __restrict__ Wpq, const float* __restrict__ Wo,
    unsigned short* __restrict__ xb, unsigned short* __restrict__ reb,
    unsigned short* __restrict__ Wt) {
  __shared__ unsigned short Ts[64][68];
  const int bid = blockIdx.x;
  const int t = threadIdx.x;
  if (bid < 1680) {
    size_t idx = ((size_t)bid * 256 + t) * 8;
    const float* src;
    unsigned short* dst;
    if (idx < 3145728) {
      src = x + idx; dst = xb + idx;
    } else {
      size_t r = idx - 3145728;
      if (r >= 294912) return;
      src = re + r; dst = reb + r;
    }
    float4 u0 = *(const float4*)src;
    float4 u1 = *(const float4*)(src + 4);
    short8 v;
    v[0] = (short)f2bf(u0.x); v[1] = (short)f2bf(u0.y);
    v[2] = (short)f2bf(u0.z); v[3] = (short)f2bf(u0.w);
    v[4] = (short)f2bf(u1.x); v[5] = (short)f2bf(u1.y);
    v[6] = (short)f2bf(u1.z); v[7] = (short)f2bf(u1.w);
    *(short8*)dst = v;
    return;
  }
  // weight transpose: 384x384 fp32 [k][n] -> bf16 [n][k]
  const int wb = bid - 1680;
  const int mat = wb / 36, rem = wb % 36;
  const float* W = mat == 0 ? Wq : mat == 1 ? Wk : mat == 2 ? Wv
                 : mat == 3 ? Wpk : mat == 4 ? Wpq : Wo;
  const int tk = (rem % 6) * 64, tn = (rem / 6) * 64;
#pragma unroll
  for (int it = 0; it < 4; ++it) {
    int r = (t >> 4) + it * 16, c = (t & 15) * 4;
    float4 v = *(const float4*)(W + (size_t)(tk + r) * 384 + tn + c);
    us4 p = {f2bf(v.x), f2bf(v.y), f2bf(v.z), f2bf(v.w)};
    *(us4*)&Ts[r][c] = p;
  }
  __syncthreads();
  unsigned short* outp = Wt + (size_t)mat * 147456;
#pragma unroll
  for (int it = 0; it < 2; ++it) {
    int n = (t >> 3) + it * 32, kc = (t & 7) * 8;
    unsigned short tmp[8];
#pragma unroll
    for (int j = 0; j < 8; ++j) tmp[j] = Ts[kc + j][n];
    *(short8*)(outp + (size_t)(tn + n) * 384 + tk + kc) = *(short8*)tmp;
  }
}

// -----------------------------------------------------------------------------
// GEMM body (R9 panel-loop, verbatim): A-frags (bf16) loaded ONCE per block
// into registers; loop NP n-panels restaging only B (L2-resident Wt).
// -----------------------------------------------------------------------------
template <int OMODE, int NP>
__device__ __forceinline__ void pgemm_body(
    const unsigned short* __restrict__ A, const unsigned short* __restrict__ Bt,
    const float* __restrict__ bias, void* __restrict__ out,
    int m0, int ng0, float scale, unsigned short (*Bs)[392]) {
  const int t = threadIdx.x;
  const int lane = t & 63, w = t >> 6, li = lane & 15, quad = lane >> 4;
  const int row = m0 + w * 16 + li;
  const int sr = t >> 2, scq = (t & 3) * 96;

#pragma unroll
  for (int i = 0; i < 12; ++i)
    *(short8*)&Bs[sr][scq + i * 8] =
        *(const short8*)(Bt + (size_t)(ng0 * 64 + sr) * 384 + scq + i * 8);

  short8 afr[12];
#pragma unroll
  for (int kk = 0; kk < 12; ++kk)
    afr[kk] = *(const short8*)(A + (size_t)row * 384 + kk * 32 + quad * 8);

#pragma unroll
  for (int pp = 0; pp < NP; ++pp) {
    __syncthreads();  // stage of panel pp visible
    v4f acc[4] = {};
#pragma unroll
    for (int kk = 0; kk < 12; ++kk) {
#pragma unroll
      for (int nt = 0; nt < 4; ++nt) {
        short8 bf = *(const short8*)&Bs[nt * 16 + li][kk * 32 + quad * 8];
        acc[nt] = __builtin_amdgcn_mfma_f32_16x16x32_bf16(afr[kk], bf, acc[nt], 0, 0, 0);
      }
    }
    __syncthreads();  // all Bs reads done; free for restage
    if (pp + 1 < NP) {
#pragma unroll
      for (int i = 0; i < 12; ++i)
        *(short8*)&Bs[sr][scq + i * 8] =
            *(const short8*)(Bt + (size_t)((ng0 + pp + 1) * 64 + sr) * 384 + scq + i * 8);
    }
    const int n0 = (ng0 + pp) * 64;
#pragma unroll
    for (int nt = 0; nt < 4; ++nt) {
      int col = n0 + nt * 16 + li;
      float bv = bias[col];
      int h = col >> 6, d = col & 63;
#pragma unroll
      for (int i = 0; i < 4; ++i) {
        int orow = m0 + w * 16 + quad * 4 + i;
        float val = (acc[nt][i] + bv) * scale;
        if constexpr (OMODE == OM_PLAIN) {
          ((float*)out)[(size_t)orow * 384 + col] = val;
        } else if constexpr (OMODE == OM_Q || OMODE == OM_K) {
          int b = orow >> 10, n = orow & 1023;
          ((unsigned short*)out)[((size_t)(b * 6 + h) << 16) + (n << 6) + d] = f2bf(val);
        } else if constexpr (OMODE == OM_VT) {
          int b = orow >> 10, n = orow & 1023;
          ((unsigned short*)out)[((size_t)(b * 6 + h) << 16) + (d << 10) + n] = f2bf(val);
        } else {  // OM_PK / OM_PQ: [h][p][d]
          ((unsigned short*)out)[(size_t)h * 49152 + (size_t)orow * 64 + d] = f2bf(val);
        }
      }
    }
  }
}

// Grid (128, 10): y<6 -> which=y>>1 (q/k/v), ng0=(y&1)*3, M=8192;
// y>=6 -> p=y-6: which=3+(p>>1) (pk/pq), ng0=(p&1)*3, M=768 (x<12).
__global__ __launch_bounds__(256, 3) void proj_all(
    const unsigned short* __restrict__ xb, const unsigned short* __restrict__ reb,
    const unsigned short* __restrict__ Wt,
    const float* __restrict__ bq, const float* __restrict__ bk,
    const float* __restrict__ bv, const float* __restrict__ bpk,
    const float* __restrict__ bpq,
    unsigned short* __restrict__ qw, unsigned short* __restrict__ kw,
    unsigned short* __restrict__ vtw, unsigned short* __restrict__ pkw,
    unsigned short* __restrict__ pqw) {
  __shared__ __align__(16) unsigned short Bs[64][392];
  const int y = blockIdx.y;
  const int m0 = blockIdx.x * 64;
  int which, ng0;
  if (y < 6) {
    which = y >> 1; ng0 = (y & 1) * 3;
  } else {
    int p = y - 6;
    which = 3 + (p >> 1); ng0 = (p & 1) * 3;
    if (m0 >= 768) return;
  }
  const unsigned short* A = which < 3 ? xb : reb;
  const unsigned short* Bt = Wt + (size_t)which * 147456;
  switch (which) {
    case 0: pgemm_body<OM_Q, 3>(A, Bt, bq,  qw,  m0, ng0, INV_SCALE, Bs); break;
    case 1: pgemm_body<OM_K, 3>(A, Bt, bk,  kw,  m0, ng0, 1.f, Bs); break;
    case 2: pgemm_body<OM_VT,3>(A, Bt, bv,  vtw, m0, ng0, 1.f, Bs); break;
    case 3: pgemm_body<OM_PK,3>(A, Bt, bpk, pkw, m0, ng0, 1.f, Bs); break;
    default: pgemm_body<OM_PQ,3>(A, Bt, bpq, pqw, m0, ng0, INV_SCALE, Bs); break;
  }
}

// Grid (128, 2): ng0 = y*3, 3 panels per block; A (aow bf16) read 2x not 6x.
__global__ __launch_bounds__(256, 3) void out_gemm(
    const unsigned short* __restrict__ ao, const unsigned short* __restrict__ Bt,
    const float* __restrict__ bo, float* __restrict__ out) {
  __shared__ __align__(16) unsigned short Bs[64][392];
  pgemm_body<OM_PLAIN, 3>(ao, Bt, bo, out,
                          blockIdx.x * 64, blockIdx.y * 3, 1.f, Bs);
}

// -----------------------------------------------------------------------------
// Fused disentangled attention — ROUND-8 KERNEL VERBATIM (best measured:
// 139.4-140.7 us, FETCH 14.6 MB). XCD working-set swizzle (validated: FETCH
// 60->14.6 MB) + T14 stage split on the 146 us ROUND-4 structure (ASTR=72,
// LDS band staging, 4 barriers, register-lean). Do not touch.
// -----------------------------------------------------------------------------
#define ASTR 72  // LDS row stride in shorts (144 B): 16B-aligned, 2-way-free banks

__global__ __launch_bounds__(256, 3) void attn_fused(
    const unsigned short* __restrict__ q, const unsigned short* __restrict__ k,
    const unsigned short* __restrict__ vt, const unsigned short* __restrict__ pk,
    const unsigned short* __restrict__ pq, unsigned short* __restrict__ ao) {
  __shared__ __align__(16) unsigned short band1[128][ASTR];  // pk band, then T1^T
  __shared__ __align__(16) unsigned short band2[128][ASTR];  // pq band, then T2^T
  __shared__ __align__(16) unsigned short Ps[64][ASTR];

  // XCD working-set remap: flat id -> (bh, n0) so each XCD owns 6 bh.
  const int f = blockIdx.x + (blockIdx.y << 4);  // hw linear id, 0..767
  const int g = f & 7, s = f >> 3;               // XCD group, slot
  const int bh = g * 6 + (s >> 4);
  const int n0 = (s & 15) * 64;
  const int h = bh % 6, b = bh / 6;
  const int t = threadIdx.x;
  const int lane = t & 63, w = t >> 6;
  const int li = lane & 15, quad = lane >> 4;

  const unsigned short* qb = q + ((size_t)bh << 16);
  const unsigned short* kb = k + ((size_t)bh << 16);
  const unsigned short* vb = vt + ((size_t)bh << 16);
  const unsigned short* pkh = pk + (size_t)h * 49152;
  const unsigned short* pqh = pq + (size_t)h * 49152;

  // q A-frags: loaded once (q pre-scaled by INV_SCALE)
  short8 aq0 = *(const short8*)(qb + (size_t)(n0 + w * 16 + li) * 64 + quad * 8);
  short8 aq1 = *(const short8*)(qb + (size_t)(n0 + w * 16 + li) * 64 + 32 + quad * 8);

  float l_part[4] = {0.f, 0.f, 0.f, 0.f};
  v4f o[4] = {};

  // T14 stage split: per-thread staging slice (row sr, 32-short quarter sc).
  const int sr = t >> 1, sc = (t & 1) * 32;
  short8 st1[4], st2[4];
  {
    int src = n0 - 0 - 63 + 384 + sr;
    src = src < 0 ? 0 : (src > 767 ? 767 : src);
    const unsigned short* p1 = pkh + (size_t)src * 64 + sc;
    const unsigned short* p2 = pqh + (size_t)src * 64 + sc;
#pragma unroll
    for (int ss = 0; ss < 4; ++ss) {
      st1[ss] = *(const short8*)(p1 + ss * 8);
      st2[ss] = *(const short8*)(p2 + ss * 8);
    }
  }

  for (int j0 = 0; j0 < 1024; j0 += 64) {
    __syncthreads();  // S0: prev gather reads done; band buffers free
    // ---- write pre-fetched pos bands to LDS ----
#pragma unroll
    for (int ss = 0; ss < 4; ++ss) {
      *(short8*)&band1[sr][sc + ss * 8] = st1[ss];
      *(short8*)&band2[sr][sc + ss * 8] = st2[ss];
    }
    __syncthreads();  // S1: bands visible

    // ---- issue next tile's stage loads (consumed at next S0) ----
    {
      int src = n0 - (j0 + 64) - 63 + 384 + sr;  // last iter: clamped, unused
      src = src < 0 ? 0 : (src > 767 ? 767 : src);
      const unsigned short* p1 = pkh + (size_t)src * 64 + sc;
      const unsigned short* p2 = pqh + (size_t)src * 64 + sc;
#pragma unroll
      for (int ss = 0; ss < 4; ++ss) {
        st1[ss] = *(const short8*)(p1 + ss * 8);
        st2[ss] = *(const short8*)(p2 + ss * 8);
      }
    }

    // k A-frags for T2 (rows j0 + w*16 + li)
    short8 ak0 = *(const short8*)(kb + (size_t)(j0 + w * 16 + li) * 64 + quad * 8);
    short8 ak1 = *(const short8*)(kb + (size_t)(j0 + w * 16 + li) * 64 + 32 + quad * 8);

    // ---- T1 = q' @ pkband^T, T2 = k @ pq'band^T (B-frags from LDS) ----
    v4f t1a[8] = {}, t2a[8] = {};
#pragma unroll
    for (int ct = 0; ct < 8; ++ct) {
      short8 b10 = *(const short8*)&band1[ct * 16 + li][quad * 8];
      short8 b11 = *(const short8*)&band1[ct * 16 + li][32 + quad * 8];
      t1a[ct] = __builtin_amdgcn_mfma_f32_16x16x32_bf16(aq0, b10, t1a[ct], 0, 0, 0);
      t1a[ct] = __builtin_amdgcn_mfma_f32_16x16x32_bf16(aq1, b11, t1a[ct], 0, 0, 0);
      short8 b20 = *(const short8*)&band2[ct * 16 + li][quad * 8];
      short8 b21 = *(const short8*)&band2[ct * 16 + li][32 + quad * 8];
      t2a[ct] = __builtin_amdgcn_mfma_f32_16x16x32_bf16(ak0, b20, t2a[ct], 0, 0, 0);
      t2a[ct] = __builtin_amdgcn_mfma_f32_16x16x32_bf16(ak1, b21, t2a[ct], 0, 0, 0);
    }
    __syncthreads();  // S2: all band B-frag reads complete before overwrite

    // ---- write T1^T/T2^T into the (dead) band buffers ----
#pragma unroll
    for (int ct = 0; ct < 8; ++ct) {
      us4 p1 = {f2bf(t1a[ct][0]), f2bf(t1a[ct][1]), f2bf(t1a[ct][2]), f2bf(t1a[ct][3])};
      us4 p2 = {f2bf(t2a[ct][0]), f2bf(t2a[ct][1]), f2bf(t2a[ct][2]), f2bf(t2a[ct][3])};
      *(us4*)&band1[ct * 16 + li][w * 16 + quad * 4] = p1;
      *(us4*)&band2[ct * 16 + li][w * 16 + quad * 4] = p2;
    }
    // ---- S_qk (B-frags = k rows direct from global/L1) ----
    v4f sqk[4] = {};
#pragma unroll
    for (int nt = 0; nt < 4; ++nt) {
      short8 b0 = *(const short8*)(kb + (size_t)(j0 + nt * 16 + li) * 64 + quad * 8);
      short8 b1 = *(const short8*)(kb + (size_t)(j0 + nt * 16 + li) * 64 + 32 + quad * 8);
      sqk[nt] = __builtin_amdgcn_mfma_f32_16x16x32_bf16(aq0, b0, sqk[nt], 0, 0, 0);
      sqk[nt] = __builtin_amdgcn_mfma_f32_16x16x32_bf16(aq1, b1, sqk[nt], 0, 0, 0);
    }
    __syncthreads();  // S3: T^T visible cross-wave

    // ---- gather + exp (scale pre-folded) + Ps ----
#pragma unroll
    for (int nt = 0; nt < 4; ++nt) {
      int jl = nt * 16 + li;
#pragma unroll
      for (int i = 0; i < 4; ++i) {
        int nl = w * 16 + quad * 4 + i;
        int r = nl - jl + 63;
        float s2 = sqk[nt][i] + bf2f(band1[r][nl]) + bf2f(band2[r][jl]);
        float p = __expf(s2);
        l_part[i] += p;
        Ps[nl][jl] = f2bf(p);
      }
    }
    // ---- PV (A-frag Ps: same-wave rows; B-frag vt direct from global) ----
#pragma unroll
    for (int kst = 0; kst < 2; ++kst) {
      short8 ap = *(const short8*)&Ps[w * 16 + li][kst * 32 + quad * 8];
#pragma unroll
      for (int nt = 0; nt < 4; ++nt) {
        short8 bv2 = *(const short8*)(vb + (size_t)(nt * 16 + li) * 1024 + j0 + kst * 32 + quad * 8);
        o[nt] = __builtin_amdgcn_mfma_f32_16x16x32_bf16(ap, bv2, o[nt], 0, 0, 0);
      }
    }
  }

  // final: reduce l across the 16 col-lanes, normalize, store (B,N,C) bf16
#pragma unroll
  for (int i = 0; i < 4; ++i) {
    float l = l_part[i];
    l += __shfl_xor(l, 1);
    l += __shfl_xor(l, 2);
    l += __shfl_xor(l, 4);
    l += __shfl_xor(l, 8);
    float inv_l = 1.f / l;
    int nl = w * 16 + quad * 4 + i;
#pragma unroll
    for (int nt = 0; nt < 4; ++nt)
      ao[((size_t)(b * 1024 + n0 + nl)) * 384 + h * 64 + nt * 16 + li] =
          f2bf(o[nt][i] * inv_l);
  }
}

// -----------------------------------------------------------------------------
extern "C" void kernel_launch(void* const* d_in, const int* in_sizes, int n_in,
                              void* d_out, int out_size, void* d_ws,
                              size_t ws_size, hipStream_t stream) {
  const float* x   = (const float*)d_in[0];
  const float* re  = (const float*)d_in[2];
  const float* Wq  = (const float*)d_in[3];
  const float* bq  = (const float*)d_in[4];
  const float* Wk  = (const float*)d_in[5];
  const float* bk  = (const float*)d_in[6];
  const float* Wv  = (const float*)d_in[7];
  const float* bv  = (const float*)d_in[8];
  const float* Wpk = (const float*)d_in[9];
  const float* bpk = (const float*)d_in[10];
  const float* Wpq = (const float*)d_in[11];
  const float* bpq = (const float*)d_in[12];
  const float* Wo  = (const float*)d_in[13];
  const float* bo  = (const float*)d_in[14];
  float* out = (float*)d_out;

  unsigned short* ws = (unsigned short*)d_ws;
  unsigned short* Wt  = ws;                 // 6*384*384
  unsigned short* qw  = Wt + 884736;        // 48*1024*64 (pre-scaled)
  unsigned short* kw  = qw + 3145728;
  unsigned short* vtw = kw + 3145728;       // (B,H,D,N)
  unsigned short* pkw = vtw + 3145728;      // 6*768*64
  unsigned short* pqw = pkw + 294912;       // (pre-scaled)
  unsigned short* aow = pqw + 294912;       // 8192*384 bf16
  unsigned short* xb  = aow + 3145728;      // 8192*384 bf16
  unsigned short* reb = xb + 3145728;       // 768*384 bf16  (end ~41.3 MB)

  prep_all<<<dim3(1896), 256, 0, stream>>>(x, re, Wq, Wk, Wv, Wpk, Wpq, Wo,
                                           xb, reb, Wt);
  proj_all<<<dim3(128, 10), 256, 0, stream>>>(xb, reb, Wt, bq, bk, bv, bpk, bpq,
                                              qw, kw, vtw, pkw, pqw);
  attn_fused<<<dim3(16, 48), 256, 0, stream>>>(qw, kw, vtw, pkw, pqw, aow);
  out_gemm<<<dim3(128, 2), 256, 0, stream>>>(aow, Wt + 5 * 147456, bo, out);
}